// Round 43
// baseline (565.585 us; speedup 1.0000x reference)
//
#include <hip/hip_runtime.h>

#define DIM 2048
#define BAND 11
#define BW 23

__device__ double g_frob;        // zero-init at load; reset by diag_kernel each call
__device__ double g_diag[DIM];

__device__ __attribute__((noinline)) bool is_prime(int n){
    if (n < 2) return false;
    if (n < 4) return true;
    if ((n & 1) == 0) return false;
    for (int d = 3; d * d <= n; d += 2)
        if (n % d == 0) return false;
    return true;
}
__device__ bool isp100(int n){ return n <= 541 && is_prime(n); }
__device__ bool isp20 (int n){ return n <= 71  && is_prime(n); }

__device__ __attribute__((noinline)) double A_at(int i, int j, double theta){
    const double PI = 3.14159265358979323846;
    if (i < 0 || j < 0 || i >= DIM || j >= DIM) return 0.0;
    int d = i - j; if (d < 0) d = -d;
    if (d > 4) return 0.0;
    if (d == 0){
        double x = 2.0 * PI * (double)i / (double)DIM;
        return theta * cos(x) + theta * cos(2.0 * x) / 2.0 + theta * cos(4.0 * x) / 4.0;
    }
    int lo = (i < j) ? i : j;
    double b = PI * (double)(2 * lo + d) / (double)DIM;
    double s = 0.0;
    if (d <= 1) s += theta * exp(-(double)d / 10.0) * sin(b);
    if (d <= 2) s += theta * exp(-(double)d / 20.0) * sin(2.0 * b) / 2.0;
    s += theta * exp(-(double)d / 40.0) * sin(4.0 * b) / 4.0;
    return s;
}

__device__ __attribute__((noinline)) void H0_at(int r, int c, double s_re, double s_im,
                                                double theta, double& hr, double& hi){
    hr = 0.0; hi = 0.0;
    if (r == c){
        const double PI = 3.14159265358979323846;
        double n = (double)(r + 1);
        double ln_n = log(n);
        double mag = exp(-s_re * ln_n);
        double ang = s_im * ln_n;
        hr = mag * cos(ang);
        hi = -mag * sin(ang);
        if (isp100(r + 1)) hr += theta * ln_n * ((PI * PI / 6.0) / n);
    } else {
        int o = c - r;
        if (o > 0){
            if (o <= 3 && isp100(r + 1)) hi = theta * log((double)(r + 1)) / (2.0 * (double)o);
        } else {
            o = -o;
            if (o <= 3 && isp100(c + 1)) hi = -theta * log((double)(c + 1)) / (2.0 * (double)o);
        }
    }
}

// f32 REAL-PART-ONLY output: out[i*DIM+j], out_size == DIM*DIM.
__global__ void band_kernel(const double* sr_p, const double* si_p,
                            const double* th_p, float* out, long long cap){
    int t = blockIdx.x * blockDim.x + threadIdx.x;
    double loc = 0.0;
    if (t < DIM * BW){
        int i = t / BW;
        int j = i + (t % BW) - BAND;
        if (j >= 0 && j < DIM){
            const double s_re = sr_p[0], s_im = si_p[0], theta = th_p[0];
            const double abs_s = sqrt(s_re * s_re + s_im * s_im);

            double ai[9], aj[9];
            #pragma clang loop unroll(disable)
            for (int u = 0; u < 9; ++u){
                ai[u] = A_at(i, i - 4 + u, theta);
                aj[u] = A_at(j, j - 4 + u, theta);
            }

            double h1r = 0.0, h1i = 0.0, htr = 0.0, hti = 0.0;
            #pragma clang loop unroll(disable)
            for (int uu = 0; uu < 9; ++uu){
                int u = i - 4 + uu;
                if (u < 0 || u >= DIM) continue;
                double aiu = ai[uu];
                #pragma clang loop unroll(disable)
                for (int vv = 0; vv < 9; ++vv){
                    int v = j - 4 + vv;
                    if (v < 0 || v >= DIM) continue;
                    double hr, hi;
                    H0_at(u, v, s_re, s_im, theta, hr, hi);
                    double w = aiu * aj[vv];
                    h1r += w * hr;
                    h1i += w * hi;
                    htr += w * hr;
                    hti += (u == v) ? (w * hi) : (-w * hi);
                }
            }

            int d = j - i;
            int ad = d < 0 ? -d : d;
            double aim = 0.0;
            if (ad >= 1 && ad <= 4){
                double cl = theta;
                #pragma clang loop unroll(disable)
                for (int q = 1; q < ad; ++q) cl *= theta;
                cl *= exp(-(double)ad / 5.0);
                aim = (d > 0) ? cl : -cl;
                if (d == 1 && isp20(i + 1)) aim += theta * log((double)(i + 1));
                if (d == -1 && isp20(j + 1)) aim -= theta * log((double)(j + 1));
            }

            double re = 0.5 * (h1r + htr);
            double im = 0.5 * (h1i - hti) + abs_s * aim;

            long long idx = (long long)i * DIM + j;
            if (idx < cap) out[idx] = (float)re;
            if (i == j) g_diag[i] = re;
            loc = re * re + im * im;
        }
    }
    double v = loc;
    #pragma clang loop unroll(disable)
    for (int off = 32; off > 0; off >>= 1)
        v += __shfl_down(v, off, 64);
    if ((threadIdx.x & 63) == 0 && v != 0.0)
        atomicAdd(&g_frob, v);
}

// Single block: read g_frob, sync, thread 0 resets it for the next replay,
// then write diag = (float)(f64_diag + reg). 256 threads x 8 strides = 2048.
__global__ void diag_kernel(float* out, long long cap){
    double frob = g_frob;
    __syncthreads();
    if (threadIdx.x == 0) g_frob = 0.0;
    double reg = sqrt(frob) * 1e-15;
    if (reg < 1e-18) reg = 1e-18;
    for (int i = threadIdx.x; i < DIM; i += 256){
        long long idx = (long long)i * DIM + i;
        if (idx < cap) out[idx] = (float)(g_diag[i] + reg);
    }
}

extern "C" void kernel_launch(void* const* d_in, const int* in_sizes, int n_in,
                              void* d_out, int out_size, void* d_ws, size_t ws_size,
                              hipStream_t stream){
    const double* sr = (const double*)d_in[0];
    const double* si = (const double*)d_in[1];
    const double* th = (const double*)d_in[2];
    float* out = (float*)d_out;
    long long cap = (long long)out_size;

    (void)hipMemsetAsync(d_out, 0, (size_t)out_size * sizeof(float), stream);

    band_kernel<<<(DIM * BW + 255) / 256, 256, 0, stream>>>(sr, si, th, out, cap);
    diag_kernel<<<1, 256, 0, stream>>>(out, cap);
}

// Round 44
// 45.864 us; speedup vs baseline: 12.3319x; 12.3319x over previous
//
#include <hip/hip_runtime.h>

#define DIM 2048
#define BAND 11
#define BW 23

__device__ double g_frob;        // zero-init at load; reset by diag_kernel each call
__device__ double g_diag[DIM];
__device__ double g_A[DIM][9];      // A(n, n-4..n+4)
__device__ double g_h0re[DIM][7];   // H0(n, n-3..n+3), offset o=col-n+3
__device__ double g_h0im[DIM][7];

__device__ __forceinline__ bool is_prime(int n){
    if (n < 2) return false;
    if (n < 4) return true;
    if ((n & 1) == 0) return false;
    for (int d = 3; d * d <= n; d += 2)
        if (n % d == 0) return false;
    return true;
}
__device__ __forceinline__ bool isp100(int n){ return n <= 541 && is_prime(n); }
__device__ __forceinline__ bool isp20 (int n){ return n <= 71  && is_prime(n); }

// One thread per row n: fill A band row and H0 band row (all transcendentals here).
__global__ void prep_kernel(const double* sr_p, const double* si_p, const double* th_p){
    int n = blockIdx.x * blockDim.x + threadIdx.x;
    if (n >= DIM) return;
    const double PI = 3.14159265358979323846;
    const double s_re = sr_p[0], s_im = si_p[0], theta = th_p[0];

    // A row (same formulas as reference's _arnold_map, entries real)
    for (int u = 0; u < 9; ++u){
        int c = n - 4 + u;
        double a = 0.0;
        if (c >= 0 && c < DIM){
            int d = n - c; if (d < 0) d = -d;
            if (d == 0){
                double x = 2.0 * PI * (double)n / (double)DIM;
                a = theta * cos(x) + theta * cos(2.0 * x) / 2.0 + theta * cos(4.0 * x) / 4.0;
            } else {
                int lo = (n < c) ? n : c;
                double b = PI * (double)(2 * lo + d) / (double)DIM;
                if (d <= 1) a += theta * exp(-(double)d / 10.0) * sin(b);
                if (d <= 2) a += theta * exp(-(double)d / 20.0) * sin(2.0 * b) / 2.0;
                a += theta * exp(-(double)d / 40.0) * sin(4.0 * b) / 4.0;
            }
        }
        g_A[n][u] = a;
    }

    // H0 row: diag n^{-s} (+ zeta2 prime corr) and pure-imag prime off-diags
    for (int o = 0; o < 7; ++o){ g_h0re[n][o] = 0.0; g_h0im[n][o] = 0.0; }
    {
        double nn = (double)(n + 1);
        double ln_n = log(nn);
        double mag = exp(-s_re * ln_n);
        double ang = s_im * ln_n;
        double hr = mag * cos(ang);
        double hi = -mag * sin(ang);
        if (isp100(n + 1)) hr += theta * ln_n * ((PI * PI / 6.0) / nn);
        g_h0re[n][3] = hr;
        g_h0im[n][3] = hi;
    }
    bool rowp = isp100(n + 1);
    for (int o = 1; o <= 3; ++o){
        if (n + o < DIM && rowp)
            g_h0im[n][3 + o] = theta * log((double)(n + 1)) / (2.0 * (double)o);
        int c = n - o;
        if (c >= 0 && isp100(c + 1))
            g_h0im[n][3 - o] = -theta * log((double)(c + 1)) / (2.0 * (double)o);
    }
}

// f32 REAL-PART-ONLY output: out[i*DIM+j], out_size == DIM*DIM.
__global__ void band_kernel(const double* sr_p, const double* si_p,
                            const double* th_p, float* out, long long cap){
    int t = blockIdx.x * blockDim.x + threadIdx.x;
    double loc = 0.0;
    if (t < DIM * BW){
        int i = t / BW;
        int j = i + (t % BW) - BAND;
        if (j >= 0 && j < DIM){
            const double s_re = sr_p[0], s_im = si_p[0], theta = th_p[0];
            const double abs_s = sqrt(s_re * s_re + s_im * s_im);

            double ai[9], aj[9];
            #pragma unroll
            for (int u = 0; u < 9; ++u){ ai[u] = g_A[i][u]; aj[u] = g_A[j][u]; }

            double h1r = 0.0, h1i = 0.0, htr = 0.0, hti = 0.0;
            #pragma unroll
            for (int uu = 0; uu < 9; ++uu){
                int u = i - 4 + uu;
                if (u < 0 || u >= DIM) continue;
                double aiu = ai[uu];
                #pragma unroll
                for (int vv = 0; vv < 9; ++vv){
                    int v = j - 4 + vv;
                    if (v < 0 || v >= DIM) continue;
                    int o = v - u;
                    if (o < -3 || o > 3) continue;   // outside H0 band = exact 0
                    double hr = g_h0re[u][o + 3];
                    double hi = g_h0im[u][o + 3];
                    double w = aiu * aj[vv];
                    h1r += w * hr;
                    h1i += w * hi;
                    htr += w * hr;
                    hti += (u == v) ? (w * hi) : (-w * hi);
                }
            }

            int d = j - i;
            int ad = d < 0 ? -d : d;
            double aim = 0.0;
            if (ad >= 1 && ad <= 4){
                double cl = theta;
                for (int q = 1; q < ad; ++q) cl *= theta;
                cl *= exp(-(double)ad / 5.0);
                aim = (d > 0) ? cl : -cl;
                if (d == 1 && isp20(i + 1)) aim += theta * log((double)(i + 1));
                if (d == -1 && isp20(j + 1)) aim -= theta * log((double)(j + 1));
            }

            double re = 0.5 * (h1r + htr);
            double im = 0.5 * (h1i - hti) + abs_s * aim;

            long long idx = (long long)i * DIM + j;
            if (idx < cap) out[idx] = (float)re;
            if (i == j) g_diag[i] = re;
            loc = re * re + im * im;
        }
    }
    double v = loc;
    #pragma unroll
    for (int off = 32; off > 0; off >>= 1)
        v += __shfl_down(v, off, 64);
    if ((threadIdx.x & 63) == 0 && v != 0.0)
        atomicAdd(&g_frob, v);
}

// Single block: read g_frob, sync, thread 0 resets it for the next replay,
// then write diag = (float)(f64_diag + reg).
__global__ void diag_kernel(float* out, long long cap){
    double frob = g_frob;
    __syncthreads();
    if (threadIdx.x == 0) g_frob = 0.0;
    double reg = sqrt(frob) * 1e-15;
    if (reg < 1e-18) reg = 1e-18;
    for (int i = threadIdx.x; i < DIM; i += 256){
        long long idx = (long long)i * DIM + i;
        if (idx < cap) out[idx] = (float)(g_diag[i] + reg);
    }
}

extern "C" void kernel_launch(void* const* d_in, const int* in_sizes, int n_in,
                              void* d_out, int out_size, void* d_ws, size_t ws_size,
                              hipStream_t stream){
    const double* sr = (const double*)d_in[0];
    const double* si = (const double*)d_in[1];
    const double* th = (const double*)d_in[2];
    float* out = (float*)d_out;
    long long cap = (long long)out_size;

    (void)hipMemsetAsync(d_out, 0, (size_t)out_size * sizeof(float), stream);

    prep_kernel<<<(DIM + 255) / 256, 256, 0, stream>>>(sr, si, th);
    band_kernel<<<(DIM * BW + 255) / 256, 256, 0, stream>>>(sr, si, th, out, cap);
    diag_kernel<<<1, 256, 0, stream>>>(out, cap);
}

// Round 45
// 41.615 us; speedup vs baseline: 13.5909x; 1.1021x over previous
//
#include <hip/hip_runtime.h>

#define DIM 2048
#define BAND 11
#define BW 23

__device__ double g_frob;        // zero-init at load; reset by diag_kernel each call
__device__ double g_diag[DIM];
__device__ double g_A[DIM][9];      // A(n, n-4..n+4)
__device__ double g_h0re[DIM][7];   // H0(n, n-3..n+3), offset o=col-n+3
__device__ double g_h0im[DIM][7];

__device__ __forceinline__ bool is_prime(int n){
    if (n < 2) return false;
    if (n < 4) return true;
    if ((n & 1) == 0) return false;
    for (int d = 3; d * d <= n; d += 2)
        if (n % d == 0) return false;
    return true;
}
__device__ __forceinline__ bool isp100(int n){ return n <= 541 && is_prime(n); }
__device__ __forceinline__ bool isp20 (int n){ return n <= 71  && is_prime(n); }

// One thread per (row n, task): tasks 0-8 = A entries, 9 = H0 diag,
// 10-12 = H0 upper off-diag o=1..3, 13-15 = H0 lower off-diag o=1..3.
__global__ void prep_kernel(const double* sr_p, const double* si_p, const double* th_p){
    int t = blockIdx.x * blockDim.x + threadIdx.x;
    if (t >= DIM * 16) return;
    int n    = t >> 4;
    int task = t & 15;
    const double PI = 3.14159265358979323846;
    const double s_re = sr_p[0], s_im = si_p[0], theta = th_p[0];

    if (task < 9){
        int u = task;
        int c = n - 4 + u;
        double a = 0.0;
        if (c >= 0 && c < DIM){
            int d = n - c; if (d < 0) d = -d;
            if (d == 0){
                double x = 2.0 * PI * (double)n / (double)DIM;
                a = theta * cos(x) + theta * cos(2.0 * x) / 2.0 + theta * cos(4.0 * x) / 4.0;
            } else {
                int lo = (n < c) ? n : c;
                double b = PI * (double)(2 * lo + d) / (double)DIM;
                if (d <= 1) a += theta * exp(-(double)d / 10.0) * sin(b);
                if (d <= 2) a += theta * exp(-(double)d / 20.0) * sin(2.0 * b) / 2.0;
                a += theta * exp(-(double)d / 40.0) * sin(4.0 * b) / 4.0;
            }
        }
        g_A[n][u] = a;
    } else if (task == 9){
        double nn = (double)(n + 1);
        double ln_n = log(nn);
        double mag = exp(-s_re * ln_n);
        double ang = s_im * ln_n;
        double hr = mag * cos(ang);
        double hi = -mag * sin(ang);
        if (isp100(n + 1)) hr += theta * ln_n * ((PI * PI / 6.0) / nn);
        g_h0re[n][3] = hr;
        g_h0im[n][3] = hi;
    } else if (task <= 12){
        int o = task - 9;                 // 1..3  -> slot 3+o
        double v = 0.0;
        if (n + o < DIM && isp100(n + 1))
            v = theta * log((double)(n + 1)) / (2.0 * (double)o);
        g_h0re[n][3 + o] = 0.0;
        g_h0im[n][3 + o] = v;
    } else {
        int o = task - 12;                // 1..3  -> slot 3-o
        double v = 0.0;
        int c = n - o;
        if (c >= 0 && isp100(c + 1))
            v = -theta * log((double)(c + 1)) / (2.0 * (double)o);
        g_h0re[n][3 - o] = 0.0;
        g_h0im[n][3 - o] = v;
    }
}

// f32 REAL-PART-ONLY output: out[i*DIM+j], out_size == DIM*DIM.
__global__ void band_kernel(const double* sr_p, const double* si_p,
                            const double* th_p, float* out, long long cap){
    int t = blockIdx.x * blockDim.x + threadIdx.x;
    double loc = 0.0;
    if (t < DIM * BW){
        int i = t / BW;
        int j = i + (t % BW) - BAND;
        if (j >= 0 && j < DIM){
            const double s_re = sr_p[0], s_im = si_p[0], theta = th_p[0];
            const double abs_s = sqrt(s_re * s_re + s_im * s_im);

            double ai[9], aj[9];
            #pragma unroll
            for (int u = 0; u < 9; ++u){ ai[u] = g_A[i][u]; aj[u] = g_A[j][u]; }

            double h1r = 0.0, h1i = 0.0, htr = 0.0, hti = 0.0;
            #pragma unroll
            for (int uu = 0; uu < 9; ++uu){
                int u = i - 4 + uu;
                if (u < 0 || u >= DIM) continue;
                double aiu = ai[uu];
                #pragma unroll
                for (int vv = 0; vv < 9; ++vv){
                    int v = j - 4 + vv;
                    if (v < 0 || v >= DIM) continue;
                    int o = v - u;
                    if (o < -3 || o > 3) continue;   // outside H0 band = exact 0
                    double hr = g_h0re[u][o + 3];
                    double hi = g_h0im[u][o + 3];
                    double w = aiu * aj[vv];
                    h1r += w * hr;
                    h1i += w * hi;
                    htr += w * hr;
                    hti += (u == v) ? (w * hi) : (-w * hi);
                }
            }

            int d = j - i;
            int ad = d < 0 ? -d : d;
            double aim = 0.0;
            if (ad >= 1 && ad <= 4){
                double cl = theta;
                for (int q = 1; q < ad; ++q) cl *= theta;
                cl *= exp(-(double)ad / 5.0);
                aim = (d > 0) ? cl : -cl;
                if (d == 1 && isp20(i + 1)) aim += theta * log((double)(i + 1));
                if (d == -1 && isp20(j + 1)) aim -= theta * log((double)(j + 1));
            }

            double re = 0.5 * (h1r + htr);
            double im = 0.5 * (h1i - hti) + abs_s * aim;

            long long idx = (long long)i * DIM + j;
            if (idx < cap) out[idx] = (float)re;
            if (i == j) g_diag[i] = re;
            loc = re * re + im * im;
        }
    }
    double v = loc;
    #pragma unroll
    for (int off = 32; off > 0; off >>= 1)
        v += __shfl_down(v, off, 64);
    if ((threadIdx.x & 63) == 0 && v != 0.0)
        atomicAdd(&g_frob, v);
}

// Single block: read g_frob, sync, thread 0 resets it for the next replay,
// then write diag = (float)(f64_diag + reg).
__global__ void diag_kernel(float* out, long long cap){
    double frob = g_frob;
    __syncthreads();
    if (threadIdx.x == 0) g_frob = 0.0;
    double reg = sqrt(frob) * 1e-15;
    if (reg < 1e-18) reg = 1e-18;
    for (int i = threadIdx.x; i < DIM; i += 256){
        long long idx = (long long)i * DIM + i;
        if (idx < cap) out[idx] = (float)(g_diag[i] + reg);
    }
}

extern "C" void kernel_launch(void* const* d_in, const int* in_sizes, int n_in,
                              void* d_out, int out_size, void* d_ws, size_t ws_size,
                              hipStream_t stream){
    const double* sr = (const double*)d_in[0];
    const double* si = (const double*)d_in[1];
    const double* th = (const double*)d_in[2];
    float* out = (float*)d_out;
    long long cap = (long long)out_size;

    (void)hipMemsetAsync(d_out, 0, (size_t)out_size * sizeof(float), stream);

    prep_kernel<<<(DIM * 16 + 255) / 256, 256, 0, stream>>>(sr, si, th);
    band_kernel<<<(DIM * BW + 255) / 256, 256, 0, stream>>>(sr, si, th, out, cap);
    diag_kernel<<<1, 256, 0, stream>>>(out, cap);
}